// Round 15
// baseline (1187.245 us; speedup 1.0000x reference)
//
#include <hip/hip_runtime.h>
#include <hip/hip_bf16.h>

// LSTM: B=64, T=2048, D=128, H=128, gates 4H=512.
// R14 analysis: total is ~100% RNN step latency (1111 cyc); biggest term is
// DS pipe fan-out (8 waves x 4 ds_read_b128 = 384 cyc/step). This version:
// RNN blocks use 4 WAVES (256 thr), each wave owns 32 hidden units ->
// 32 B-frags = 128 VGPRs of weights; waves_per_eu(1,1) removes any occupancy
// incentive for the RA to squeeze (R1-R10 squeezes all chased occupancy).
// DS: 16 instr/step (halved). Barrier skew: 4 arrivals. VALU tail: 2 units
// per q==0 lane. Pipeline structure from R14 (launch-boundary sync, xg
// double-buffer, gate-packed xg, chunk i RNN + chunk i+1 GEMM in one grid).

#define B_ 64
#define T_ 2048
#define D_ 128
#define H_ 128
#define G_ 512  // 4*H

typedef __bf16 v8bf __attribute__((ext_vector_type(8)));
typedef float f32x4 __attribute__((ext_vector_type(4)));

__device__ __forceinline__ float fast_exp2(float x) { return __builtin_amdgcn_exp2f(x); }
__device__ __forceinline__ float fast_rcp(float x)  { return __builtin_amdgcn_rcpf(x); }
__device__ __forceinline__ float sigmoid_(float x) {
    return fast_rcp(1.0f + fast_exp2(x * -1.44269504088896341f));
}
__device__ __forceinline__ float tanh_(float x) {
    // tanh(x) = 1 - 2/(1+2^(x*2*log2e)); saturates correctly at +-inf.
    return 1.0f - 2.0f * fast_rcp(1.0f + fast_exp2(x * 2.88539008177792682f));
}
__device__ __forceinline__ unsigned short f2bf(float f) {
    union { float f; unsigned u; } v; v.f = f;
    unsigned r = v.u + 0x7FFFu + ((v.u >> 16) & 1u);  // RNE
    return (unsigned short)(r >> 16);
}

// ---------------- K0: Wx -> bf16 transposed wxt[col][k] ----------------
__global__ void __launch_bounds__(256)
wxt_kernel(const float* __restrict__ Wx, unsigned short* __restrict__ wxt) {
    int t = blockIdx.x * 256 + threadIdx.x;   // 0..8191
    int col = t >> 4;            // 0..511
    int k0  = (t & 15) * 8;      // 0..120
    union { unsigned short s[8]; v8bf v; } u;
#pragma unroll
    for (int j = 0; j < 8; ++j) u.s[j] = f2bf(Wx[(size_t)(k0 + j) * G_ + col]);
    *(v8bf*)&wxt[(size_t)col * D_ + k0] = u.v;
}

// ---------------- device GEMM: one 16-row block (256 threads, 4 waves) -----
// wave = gate index g; output GATE-PACKED: xg[row*512 + u*4 + g], u=hidden.
__device__ __forceinline__ void gemm16(const float* __restrict__ x,
                                       const unsigned short* __restrict__ wxt,
                                       const float* __restrict__ bias,
                                       float* __restrict__ xg,
                                       int t0g, int Cg, int gb, int tid) {
    const int lane = tid & 63;
    const int q    = lane >> 4;
    const int cl   = lane & 15;
    const int kb   = q * 8;
    const int g4   = tid >> 6;              // gate index 0..3
    const int rowg = gb * 16;               // chunk-local row
    const int b    = rowg / Cg;             // Cg multiple of 64
    const int tl   = rowg - b * Cg;

    const float* xr = x + ((size_t)b * T_ + (size_t)(t0g + tl) + cl) * D_;
    v8bf af[4];
#pragma unroll
    for (int kk = 0; kk < 4; ++kk) {
        float4 lo = *(const float4*)&xr[kk * 32 + kb];
        float4 hi = *(const float4*)&xr[kk * 32 + kb + 4];
        union { unsigned u[4]; v8bf v; } pk;
        asm("v_cvt_pk_bf16_f32 %0, %1, %2" : "=v"(pk.u[0]) : "v"(lo.x), "v"(lo.y));
        asm("v_cvt_pk_bf16_f32 %0, %1, %2" : "=v"(pk.u[1]) : "v"(lo.z), "v"(lo.w));
        asm("v_cvt_pk_bf16_f32 %0, %1, %2" : "=v"(pk.u[2]) : "v"(hi.x), "v"(hi.y));
        asm("v_cvt_pk_bf16_f32 %0, %1, %2" : "=v"(pk.u[3]) : "v"(hi.z), "v"(hi.w));
        af[kk] = pk.v;
    }

    f32x4 acc[8];
#pragma unroll
    for (int n = 0; n < 8; ++n) {
        float bv = bias[g4 * 128 + n * 16 + cl];
        acc[n] = (f32x4){bv, bv, bv, bv};
    }
#pragma unroll
    for (int kk = 0; kk < 4; ++kk) {
#pragma unroll
        for (int n = 0; n < 8; ++n) {
            v8bf bf = *(const v8bf*)&wxt[(size_t)(g4 * 128 + n * 16 + cl) * D_ + kk * 32 + kb];
            acc[n] = __builtin_amdgcn_mfma_f32_16x16x32_bf16(af[kk], bf, acc[n], 0, 0, 0);
        }
    }
#pragma unroll
    for (int n = 0; n < 8; ++n) {
        int u = n * 16 + cl;
#pragma unroll
        for (int r = 0; r < 4; ++r)
            xg[(size_t)(rowg + q * 4 + r) * G_ + u * 4 + g4] = acc[n][r];
    }
}

// ---------------- standalone GEMM kernel (chunk 0) ----------------
__global__ void __launch_bounds__(256)
xg_gemm256(const float* __restrict__ x, const unsigned short* __restrict__ wxt,
           const float* __restrict__ bias, float* __restrict__ xg,
           int t0g, int Cg) {
    gemm16(x, wxt, bias, xg, t0g, Cg, blockIdx.x, threadIdx.x);
}

// ---------------- fused: RNN(chunk cur, 4 waves) + GEMM(chunk next) --------
__global__ void __launch_bounds__(256)
__attribute__((amdgpu_waves_per_eu(1, 1)))
lstm_fused(const float* __restrict__ x, const unsigned short* __restrict__ wxt,
           const float* __restrict__ Wh, const float* __restrict__ bias,
           float* __restrict__ hs, float* __restrict__ cs,
           float* __restrict__ hstate, float* __restrict__ cstate,
           const float* __restrict__ xgCur, float* __restrict__ xgNext,
           int t0, int C, int t0n, int Cn) {
    const int tid  = threadIdx.x;
    const int lane = tid & 63;
    const int q    = lane >> 4;
    const int cl   = lane & 15;
    const int kb   = q * 8;

    if (blockIdx.x >= 64) {
        // GEMM role: produce NEXT chunk's xg. Independent of RNN blocks.
        gemm16(x, wxt, bias, xgNext, t0n, Cn, blockIdx.x - 64, tid);
        return;
    }

    // ================= RNN role: 4 waves, 32 units/wave =================
    const int b  = blockIdx.x;
    const int w  = tid >> 6;          // wave 0..3
    const int u0 = w * 32 + cl;       // hidden unit (half 0)
    const int u1 = u0 + 16;           // hidden unit (half 1)

    __shared__ __align__(16) unsigned short h_u16[2][H_];

    // one-time: Wh B-fragments, 32 frags = 128 VGPRs.
    // whf[kk][g*2+half]: col = g*128 + w*32 + half*16 + cl.
    v8bf whf[4][8];
#pragma unroll
    for (int kk = 0; kk < 4; ++kk) {
#pragma unroll
        for (int g = 0; g < 4; ++g) {
#pragma unroll
            for (int half = 0; half < 2; ++half) {
                union { unsigned short s[8]; v8bf v; } uw;
                int col = g * 128 + w * 32 + half * 16 + cl;
#pragma unroll
                for (int j = 0; j < 8; ++j)
                    uw.s[j] = f2bf(Wh[(size_t)(kk * 32 + kb + j) * G_ + col]);
                whf[kk][g * 2 + half] = uw.v;
            }
        }
    }

    float c0 = 0.0f, c1 = 0.0f;
    if (t0 > 0) { c0 = cstate[b * H_ + u0]; c1 = cstate[b * H_ + u1]; }
    if (tid < H_) h_u16[0][tid] = f2bf((t0 > 0) ? hstate[b * H_ + tid] : 0.0f);
    __syncthreads();  // once per chunk

    const float* xgb = xgCur + (size_t)b * C * G_;

    // 2-step-deep xg prefetch (gate-packed): slotA = even t, slotB = odd t.
    f32x4 xA0 = *(const f32x4*)&xgb[(size_t)0 * G_ + u0 * 4];
    f32x4 xA1 = *(const f32x4*)&xgb[(size_t)0 * G_ + u1 * 4];
    f32x4 xB0 = *(const f32x4*)&xgb[(size_t)1 * G_ + u0 * 4];
    f32x4 xB1 = *(const f32x4*)&xgb[(size_t)1 * G_ + u1 * 4];

#define RNN_STEP(PX0, PX1, TCUR, PR, PW)                                       \
    {                                                                          \
        f32x4 a00 = {0,0,0,0}, a01 = {0,0,0,0};                                \
        f32x4 a10 = {0,0,0,0}, a11 = {0,0,0,0};                                \
        f32x4 a20 = {0,0,0,0}, a21 = {0,0,0,0};                                \
        f32x4 a30 = {0,0,0,0}, a31 = {0,0,0,0};                                \
        _Pragma("unroll")                                                      \
        for (int kk = 0; kk < 4; ++kk) {                                       \
            v8bf ha = *(const v8bf*)&h_u16[PR][kk * 32 + kb];                  \
            a00 = __builtin_amdgcn_mfma_f32_16x16x32_bf16(ha, whf[kk][0], a00, 0, 0, 0); \
            a01 = __builtin_amdgcn_mfma_f32_16x16x32_bf16(ha, whf[kk][1], a01, 0, 0, 0); \
            a10 = __builtin_amdgcn_mfma_f32_16x16x32_bf16(ha, whf[kk][2], a10, 0, 0, 0); \
            a11 = __builtin_amdgcn_mfma_f32_16x16x32_bf16(ha, whf[kk][3], a11, 0, 0, 0); \
            a20 = __builtin_amdgcn_mfma_f32_16x16x32_bf16(ha, whf[kk][4], a20, 0, 0, 0); \
            a21 = __builtin_amdgcn_mfma_f32_16x16x32_bf16(ha, whf[kk][5], a21, 0, 0, 0); \
            a30 = __builtin_amdgcn_mfma_f32_16x16x32_bf16(ha, whf[kk][6], a30, 0, 0, 0); \
            a31 = __builtin_amdgcn_mfma_f32_16x16x32_bf16(ha, whf[kk][7], a31, 0, 0, 0); \
        }                                                                      \
        float iv0 = sigmoid_(a00[0] + PX0[0]);                                 \
        float fv0 = sigmoid_(a10[0] + PX0[1]);                                 \
        float gv0 = tanh_(a20[0] + PX0[2]);                                    \
        float ov0 = sigmoid_(a30[0] + PX0[3]);                                 \
        float iv1 = sigmoid_(a01[0] + PX1[0]);                                 \
        float fv1 = sigmoid_(a11[0] + PX1[1]);                                 \
        float gv1 = tanh_(a21[0] + PX1[2]);                                    \
        float ov1 = sigmoid_(a31[0] + PX1[3]);                                 \
        c0 = fmaf(fv0, c0, iv0 * gv0);                                         \
        c1 = fmaf(fv1, c1, iv1 * gv1);                                         \
        float h0v = ov0 * tanh_(c0);                                           \
        float h1v = ov1 * tanh_(c1);                                           \
        { int pf = ((TCUR) + 2 < C) ? ((TCUR) + 2) : (C - 1);                  \
          PX0 = *(const f32x4*)&xgb[(size_t)pf * G_ + u0 * 4];                 \
          PX1 = *(const f32x4*)&xgb[(size_t)pf * G_ + u1 * 4]; }               \
        if (q == 0) {                                                          \
            h_u16[PW][u0] = f2bf(h0v);                                         \
            h_u16[PW][u1] = f2bf(h1v);                                         \
            size_t off = ((size_t)b * T_ + (size_t)(t0 + (TCUR))) * H_ + u0;   \
            hs[off] = h0v;      cs[off] = c0;                                  \
            hs[off + 16] = h1v; cs[off + 16] = c1;                             \
        }                                                                      \
        asm volatile("s_waitcnt lgkmcnt(0)\n\ts_barrier" ::: "memory");        \
    }

#pragma unroll 1
    for (int t = 0; t < C; t += 2) {  // C is a multiple of 64
        RNN_STEP(xA0, xA1, t,     0, 1)
        RNN_STEP(xB0, xB1, t + 1, 1, 0)
    }
#undef RNN_STEP

    if (q == 0) { cstate[b * H_ + u0] = c0; cstate[b * H_ + u1] = c1; }
    // final h in buf 0 (C even; last step wrote PW=0)
    if (tid < H_) {
        unsigned ui = ((unsigned)h_u16[0][tid]) << 16;
        float hf; __builtin_memcpy(&hf, &ui, 4);
        hstate[b * H_ + tid] = hf;
    }
}

extern "C" void kernel_launch(void* const* d_in, const int* in_sizes, int n_in,
                              void* d_out, int out_size, void* d_ws, size_t ws_size,
                              hipStream_t stream) {
    const float* x    = (const float*)d_in[0];  // [64,2048,128]
    const float* Wx   = (const float*)d_in[1];  // [128,512]
    const float* Wh   = (const float*)d_in[2];  // [128,512]
    const float* bias = (const float*)d_in[3];  // [512]

    float* hs = (float*)d_out;                         // [64,2048,128]
    float* cs = hs + (size_t)B_ * T_ * H_;             // [64,2048,128]

    float* hstate = (float*)d_ws;                               // [64,128]
    float* cstate = hstate + B_ * H_;                           // [64,128]
    unsigned short* wxt = (unsigned short*)(cstate + B_ * H_);  // [512][128] bf16
    float* xgA = (float*)(wxt + (size_t)G_ * D_);               // buf A

    const size_t head_bytes = (size_t)2 * B_ * H_ * 4 + (size_t)G_ * D_ * 2;
    size_t avail = (ws_size > head_bytes) ? (ws_size - head_bytes) : 0;
    const size_t bytes_per_t = (size_t)B_ * G_ * sizeof(float);

    int C = (int)(avail / (2 * bytes_per_t));   // double buffer
    if (C > 512) C = 512;                        // 4 chunks -> overlap
    C &= ~63;
    if (C < 64) C = 64;

    float* xgB = xgA + (size_t)B_ * C * G_;

    wxt_kernel<<<32, 256, 0, stream>>>(Wx, wxt);

    int nChunks = 0, t0s[64], Cis[64];
    for (int t0 = 0; t0 < T_; t0 += C) {
        t0s[nChunks] = t0;
        Cis[nChunks] = (T_ - t0 < C) ? (T_ - t0) : C;
        ++nChunks;
    }

    // chunk 0 GEMM standalone
    xg_gemm256<<<(B_ * Cis[0]) / 16, 256, 0, stream>>>(x, wxt, bias, xgA, t0s[0], Cis[0]);

    for (int i = 0; i < nChunks; ++i) {
        float* bufCur  = (i & 1) ? xgB : xgA;
        float* bufNext = (i & 1) ? xgA : xgB;
        int hasNext = (i + 1 < nChunks);
        int t0n = hasNext ? t0s[i + 1] : 0;
        int Cn  = hasNext ? Cis[i + 1] : 64;
        int nGemm = hasNext ? (B_ * Cn) / 16 : 0;
        lstm_fused<<<64 + nGemm, 256, 0, stream>>>(
            x, wxt, Wh, bias, hs, cs, hstate, cstate,
            bufCur, bufNext, t0s[i], Cis[i], t0n, Cn);
    }
}

// Round 16
// 967.468 us; speedup vs baseline: 1.2272x; 1.2272x over previous
//
#include <hip/hip_runtime.h>
#include <hip/hip_bf16.h>

// LSTM: B=64, T=2048, D=128, H=128, gates 4H=512.
// R15 lesson: 4-wave RNN needs ~190 VGPR, allocator caps ~144 -> spill ->
// regression. 8 waves x 16 frags is the forced design point. This round:
// R14-exact structure + DS-read hoisting: all four h-fragments loaded into
// named registers BEFORE the MFMA block, pinned with sched_group_barrier
// (DS_READ x4 -> MFMA x16) so frag 1-3 latency hides under kk0 MFMAs.
// Pipeline (launch-boundary sync, xg double buffer, gate-packed xg) kept.

#define B_ 64
#define T_ 2048
#define D_ 128
#define H_ 128
#define G_ 512  // 4*H

typedef __bf16 v8bf __attribute__((ext_vector_type(8)));
typedef float f32x4 __attribute__((ext_vector_type(4)));

__device__ __forceinline__ float fast_exp2(float x) { return __builtin_amdgcn_exp2f(x); }
__device__ __forceinline__ float fast_rcp(float x)  { return __builtin_amdgcn_rcpf(x); }
__device__ __forceinline__ float sigmoid_(float x) {
    return fast_rcp(1.0f + fast_exp2(x * -1.44269504088896341f));
}
__device__ __forceinline__ float tanh_(float x) {
    // tanh(x) = 1 - 2/(1+2^(x*2*log2e)); saturates correctly at +-inf.
    return 1.0f - 2.0f * fast_rcp(1.0f + fast_exp2(x * 2.88539008177792682f));
}
__device__ __forceinline__ unsigned short f2bf(float f) {
    union { float f; unsigned u; } v; v.f = f;
    unsigned r = v.u + 0x7FFFu + ((v.u >> 16) & 1u);  // RNE
    return (unsigned short)(r >> 16);
}

// ---------------- K0: Wx -> bf16 transposed wxt[col][k] ----------------
__global__ void __launch_bounds__(256)
wxt_kernel(const float* __restrict__ Wx, unsigned short* __restrict__ wxt) {
    int t = blockIdx.x * 256 + threadIdx.x;   // 0..8191
    int col = t >> 4;            // 0..511
    int k0  = (t & 15) * 8;      // 0..120
    union { unsigned short s[8]; v8bf v; } u;
#pragma unroll
    for (int j = 0; j < 8; ++j) u.s[j] = f2bf(Wx[(size_t)(k0 + j) * G_ + col]);
    *(v8bf*)&wxt[(size_t)col * D_ + k0] = u.v;
}

// ---------------- device GEMM: one 32-row block (512 threads) ----------------
// Output layout GATE-PACKED: xg[row*512 + hu*4 + gate], gate order i,f,g,o.
__device__ __forceinline__ void gemm32(const float* __restrict__ x,
                                       const unsigned short* __restrict__ wxt,
                                       const float* __restrict__ bias,
                                       float* __restrict__ xg,
                                       int t0g, int Cg, int gb, int tid) {
    const int lane = tid & 63;
    const int q    = lane >> 4;
    const int cl   = lane & 15;
    const int kb   = q * 8;
    const int wave = tid >> 6;
    const int half = wave >> 2;    // 0/1: which 16-row tile
    const int w4   = wave & 3;     // gate quarter = gate index
    const int rowg = gb * 32 + half * 16;   // chunk-local row
    const int b    = rowg / Cg;             // Cg multiple of 64
    const int tl   = rowg - b * Cg;

    const float* xr = x + ((size_t)b * T_ + (size_t)(t0g + tl) + cl) * D_;
    v8bf af[4];
#pragma unroll
    for (int kk = 0; kk < 4; ++kk) {
        float4 lo = *(const float4*)&xr[kk * 32 + kb];
        float4 hi = *(const float4*)&xr[kk * 32 + kb + 4];
        union { unsigned u[4]; v8bf v; } pk;
        asm("v_cvt_pk_bf16_f32 %0, %1, %2" : "=v"(pk.u[0]) : "v"(lo.x), "v"(lo.y));
        asm("v_cvt_pk_bf16_f32 %0, %1, %2" : "=v"(pk.u[1]) : "v"(lo.z), "v"(lo.w));
        asm("v_cvt_pk_bf16_f32 %0, %1, %2" : "=v"(pk.u[2]) : "v"(hi.x), "v"(hi.y));
        asm("v_cvt_pk_bf16_f32 %0, %1, %2" : "=v"(pk.u[3]) : "v"(hi.z), "v"(hi.w));
        af[kk] = pk.v;
    }

    f32x4 acc[8];
#pragma unroll
    for (int n = 0; n < 8; ++n) {
        float bv = bias[w4 * 128 + n * 16 + cl];
        acc[n] = (f32x4){bv, bv, bv, bv};
    }
#pragma unroll
    for (int kk = 0; kk < 4; ++kk) {
#pragma unroll
        for (int n = 0; n < 8; ++n) {
            v8bf bf = *(const v8bf*)&wxt[(size_t)(w4 * 128 + n * 16 + cl) * D_ + kk * 32 + kb];
            acc[n] = __builtin_amdgcn_mfma_f32_16x16x32_bf16(af[kk], bf, acc[n], 0, 0, 0);
        }
    }
#pragma unroll
    for (int n = 0; n < 8; ++n) {
        int hu = n * 16 + cl;
#pragma unroll
        for (int r = 0; r < 4; ++r)
            xg[(size_t)(rowg + q * 4 + r) * G_ + hu * 4 + w4] = acc[n][r];
    }
}

// ---------------- standalone GEMM kernel (chunk 0) ----------------
__global__ void __launch_bounds__(512)
xg_gemm512(const float* __restrict__ x, const unsigned short* __restrict__ wxt,
           const float* __restrict__ bias, float* __restrict__ xg,
           int t0g, int Cg) {
    gemm32(x, wxt, bias, xg, t0g, Cg, blockIdx.x, threadIdx.x);
}

// ---------------- fused: RNN(chunk cur) + GEMM(chunk next) ----------------
__global__ void __launch_bounds__(512)
__attribute__((amdgpu_waves_per_eu(2, 2)))
lstm_fused(const float* __restrict__ x, const unsigned short* __restrict__ wxt,
           const float* __restrict__ Wh, const float* __restrict__ bias,
           float* __restrict__ hs, float* __restrict__ cs,
           float* __restrict__ hstate, float* __restrict__ cstate,
           const float* __restrict__ xgCur, float* __restrict__ xgNext,
           int t0, int C, int t0n, int Cn) {
    const int tid  = threadIdx.x;
    const int lane = tid & 63;
    const int q    = lane >> 4;
    const int cl   = lane & 15;
    const int kb   = q * 8;

    if (blockIdx.x >= 64) {
        // GEMM role: produce NEXT chunk's xg. Independent of RNN blocks.
        gemm32(x, wxt, bias, xgNext, t0n, Cn, blockIdx.x - 64, tid);
        return;
    }

    // ================= RNN role: R8 core, packed xg loads =================
    const int b  = blockIdx.x;
    const int w  = tid >> 6;       // wave 0..7
    const int hu = w * 16 + cl;    // hidden unit owned

    __shared__ __align__(16) unsigned short h_u16[2][H_];

    // one-time: Wh B-fragments (16 frags = 64 VGPRs)
    v8bf whf[4][4];
#pragma unroll
    for (int kk = 0; kk < 4; ++kk) {
#pragma unroll
        for (int gc = 0; gc < 4; ++gc) {
            union { unsigned short s[8]; v8bf v; } uw;
#pragma unroll
            for (int j = 0; j < 8; ++j)
                uw.s[j] = f2bf(Wh[(size_t)(kk * 32 + kb + j) * G_ + gc * 128 + hu]);
            whf[kk][gc] = uw.v;
        }
    }

    float c = 0.0f;
    if (t0 > 0) c = cstate[b * H_ + hu];
    if (tid < H_) h_u16[0][tid] = f2bf((t0 > 0) ? hstate[b * H_ + tid] : 0.0f);
    __syncthreads();  // once per chunk

    const float* xgb = xgCur + (size_t)b * C * G_;

    // 4-step-deep xg prefetch, ONE dwordx4 per step (gate-packed layout)
    f32x4 xp0 = *(const f32x4*)&xgb[(size_t)0 * G_ + hu * 4];
    f32x4 xp1 = *(const f32x4*)&xgb[(size_t)1 * G_ + hu * 4];
    f32x4 xp2 = *(const f32x4*)&xgb[(size_t)2 * G_ + hu * 4];
    f32x4 xp3 = *(const f32x4*)&xgb[(size_t)3 * G_ + hu * 4];

#define RNN_STEP(PX, TCUR, PR, PW)                                             \
    {                                                                          \
        /* hoist ALL FOUR h-frag reads ahead of the MFMA block */              \
        v8bf ha0 = *(const v8bf*)&h_u16[PR][0 * 32 + kb];                      \
        v8bf ha1 = *(const v8bf*)&h_u16[PR][1 * 32 + kb];                      \
        v8bf ha2 = *(const v8bf*)&h_u16[PR][2 * 32 + kb];                      \
        v8bf ha3 = *(const v8bf*)&h_u16[PR][3 * 32 + kb];                      \
        __builtin_amdgcn_sched_group_barrier(0x100, 4, 0);  /* 4x DS_READ */   \
        f32x4 a0 = {0.f, 0.f, 0.f, 0.f};                                       \
        f32x4 a1 = {0.f, 0.f, 0.f, 0.f};                                       \
        f32x4 a2 = {0.f, 0.f, 0.f, 0.f};                                       \
        f32x4 a3 = {0.f, 0.f, 0.f, 0.f};                                       \
        a0 = __builtin_amdgcn_mfma_f32_16x16x32_bf16(ha0, whf[0][0], a0, 0, 0, 0); \
        a1 = __builtin_amdgcn_mfma_f32_16x16x32_bf16(ha0, whf[0][1], a1, 0, 0, 0); \
        a2 = __builtin_amdgcn_mfma_f32_16x16x32_bf16(ha0, whf[0][2], a2, 0, 0, 0); \
        a3 = __builtin_amdgcn_mfma_f32_16x16x32_bf16(ha0, whf[0][3], a3, 0, 0, 0); \
        a0 = __builtin_amdgcn_mfma_f32_16x16x32_bf16(ha1, whf[1][0], a0, 0, 0, 0); \
        a1 = __builtin_amdgcn_mfma_f32_16x16x32_bf16(ha1, whf[1][1], a1, 0, 0, 0); \
        a2 = __builtin_amdgcn_mfma_f32_16x16x32_bf16(ha1, whf[1][2], a2, 0, 0, 0); \
        a3 = __builtin_amdgcn_mfma_f32_16x16x32_bf16(ha1, whf[1][3], a3, 0, 0, 0); \
        a0 = __builtin_amdgcn_mfma_f32_16x16x32_bf16(ha2, whf[2][0], a0, 0, 0, 0); \
        a1 = __builtin_amdgcn_mfma_f32_16x16x32_bf16(ha2, whf[2][1], a1, 0, 0, 0); \
        a2 = __builtin_amdgcn_mfma_f32_16x16x32_bf16(ha2, whf[2][2], a2, 0, 0, 0); \
        a3 = __builtin_amdgcn_mfma_f32_16x16x32_bf16(ha2, whf[2][3], a3, 0, 0, 0); \
        a0 = __builtin_amdgcn_mfma_f32_16x16x32_bf16(ha3, whf[3][0], a0, 0, 0, 0); \
        a1 = __builtin_amdgcn_mfma_f32_16x16x32_bf16(ha3, whf[3][1], a1, 0, 0, 0); \
        a2 = __builtin_amdgcn_mfma_f32_16x16x32_bf16(ha3, whf[3][2], a2, 0, 0, 0); \
        a3 = __builtin_amdgcn_mfma_f32_16x16x32_bf16(ha3, whf[3][3], a3, 0, 0, 0); \
        __builtin_amdgcn_sched_group_barrier(0x8, 16, 0);   /* 16x MFMA */     \
        float iv = sigmoid_(a0[0] + PX[0]);                                    \
        float fv = sigmoid_(a1[0] + PX[1]);                                    \
        float gv = tanh_(a2[0] + PX[2]);                                       \
        float ov = sigmoid_(a3[0] + PX[3]);                                    \
        c = fmaf(fv, c, iv * gv);                                              \
        float hnv = ov * tanh_(c);                                             \
        { int pf = ((TCUR) + 4 < C) ? ((TCUR) + 4) : (C - 1);                  \
          PX = *(const f32x4*)&xgb[(size_t)pf * G_ + hu * 4]; }                \
        if (q == 0) {                                                          \
            h_u16[PW][hu] = f2bf(hnv);                                         \
            size_t off = ((size_t)b * T_ + (size_t)(t0 + (TCUR))) * H_ + hu;   \
            hs[off] = hnv; cs[off] = c;                                        \
        }                                                                      \
        asm volatile("s_waitcnt lgkmcnt(0)\n\ts_barrier" ::: "memory");        \
    }

#pragma unroll 1
    for (int t = 0; t < C; t += 4) {  // C is a multiple of 64
        RNN_STEP(xp0, t,     0, 1)
        RNN_STEP(xp1, t + 1, 1, 0)
        RNN_STEP(xp2, t + 2, 0, 1)
        RNN_STEP(xp3, t + 3, 1, 0)
    }
#undef RNN_STEP

    if (q == 0) cstate[b * H_ + hu] = c;
    // final h in buf 0 (C multiple of 4; last step wrote PW=0)
    if (tid < H_) {
        unsigned ui = ((unsigned)h_u16[0][tid]) << 16;
        float hf; __builtin_memcpy(&hf, &ui, 4);
        hstate[b * H_ + tid] = hf;
    }
}

extern "C" void kernel_launch(void* const* d_in, const int* in_sizes, int n_in,
                              void* d_out, int out_size, void* d_ws, size_t ws_size,
                              hipStream_t stream) {
    const float* x    = (const float*)d_in[0];  // [64,2048,128]
    const float* Wx   = (const float*)d_in[1];  // [128,512]
    const float* Wh   = (const float*)d_in[2];  // [128,512]
    const float* bias = (const float*)d_in[3];  // [512]

    float* hs = (float*)d_out;                         // [64,2048,128]
    float* cs = hs + (size_t)B_ * T_ * H_;             // [64,2048,128]

    float* hstate = (float*)d_ws;                               // [64,128]
    float* cstate = hstate + B_ * H_;                           // [64,128]
    unsigned short* wxt = (unsigned short*)(cstate + B_ * H_);  // [512][128] bf16
    float* xgA = (float*)(wxt + (size_t)G_ * D_);               // buf A

    const size_t head_bytes = (size_t)2 * B_ * H_ * 4 + (size_t)G_ * D_ * 2;
    size_t avail = (ws_size > head_bytes) ? (ws_size - head_bytes) : 0;
    const size_t bytes_per_t = (size_t)B_ * G_ * sizeof(float);

    int C = (int)(avail / (2 * bytes_per_t));   // double buffer
    if (C > 512) C = 512;                        // 4 chunks -> overlap
    C &= ~63;
    if (C < 64) C = 64;

    float* xgB = xgA + (size_t)B_ * C * G_;

    wxt_kernel<<<32, 256, 0, stream>>>(Wx, wxt);

    int nChunks = 0, t0s[64], Cis[64];
    for (int t0 = 0; t0 < T_; t0 += C) {
        t0s[nChunks] = t0;
        Cis[nChunks] = (T_ - t0 < C) ? (T_ - t0) : C;
        ++nChunks;
    }

    // chunk 0 GEMM standalone
    xg_gemm512<<<(B_ * Cis[0]) / 32, 512, 0, stream>>>(x, wxt, bias, xgA, t0s[0], Cis[0]);

    for (int i = 0; i < nChunks; ++i) {
        float* bufCur  = (i & 1) ? xgB : xgA;
        float* bufNext = (i & 1) ? xgA : xgB;
        int hasNext = (i + 1 < nChunks);
        int t0n = hasNext ? t0s[i + 1] : 0;
        int Cn  = hasNext ? Cis[i + 1] : 64;
        int nGemm = hasNext ? (B_ * Cn) / 32 : 0;
        lstm_fused<<<64 + nGemm, 512, 0, stream>>>(
            x, wxt, Wh, bias, hs, cs, hstate, cstate,
            bufCur, bufNext, t0s[i], Cis[i], t0n, Cn);
    }
}